// Round 11
// baseline (334.655 us; speedup 1.0000x reference)
//
#include <hip/hip_runtime.h>
#include <stdint.h>
#include <math.h>

#define N_TOK 4800
#define NH 8
#define HD 32
#define DP 40          // T' padded leading dim (D=38 -> 40)
#define DD 38
#define NTILES 150     // 32-wide m tiles
#define MCHUNK 3       // m-chunks in tprime (50 tiles each)
#define FRAG 2048      // shorts per (h,mtile) V fragment: 4 blocks x 64 lanes x 8
#define SCALE 0.17677669529663687f            // 32^-0.5
#define QSCALE (0.17677669529663687f * 1.4426950408889634f)  // SCALE*log2(e)

typedef float f32x16 __attribute__((ext_vector_type(16)));
typedef float f32x2 __attribute__((ext_vector_type(2)));
typedef short s8v __attribute__((ext_vector_type(8)));
typedef int i2v __attribute__((ext_vector_type(2)));

#if __has_builtin(__builtin_amdgcn_exp2f)
#define EXP2F(x) __builtin_amdgcn_exp2f(x)
#else
#define EXP2F(x) exp2f(x)
#endif

__device__ __forceinline__ unsigned short f2bf(float x) {
    union { float f; uint32_t u; } v; v.f = x;
    uint32_t r = v.u + 0x7FFFu + ((v.u >> 16) & 1u);
    return (unsigned short)(r >> 16);
}
__device__ __forceinline__ float bf2f(unsigned short h) {
    union { uint32_t u; float f; } v; v.u = ((uint32_t)h) << 16;
    return v.f;
}
__device__ __forceinline__ int cvtpk(float lo, float hi) {
    int r;
    asm("v_cvt_pk_bf16_f32 %0, %1, %2" : "=v"(r) : "v"(lo), "v"(hi));
    return r;
}
__device__ __forceinline__ s8v mk_s8(int a, int b, int c, int d) {
    union { int i[4]; s8v s; } u;
    u.i[0] = a; u.i[1] = b; u.i[2] = c; u.i[3] = d;
    return u.s;
}
// positional encoding component idx (0..5) for token m
__device__ __forceinline__ float posv(int m, int idx) {
    const int rrow = m / 80, rcol = m % 80;
    const float y = -1.0f + (float)rrow * (2.0f / 59.0f);
    const float x = -1.0f + (float)rcol * (2.0f / 79.0f);
    const float p3 = y * (240.0f / 517.0f);
    const float p4 = x * (360.0f / 517.0f);
    if (idx == 0) return p3 * p3;
    if (idx == 1) return p4 * p4;
    if (idx == 2) return p3 * p4;
    if (idx == 3) return p3;
    if (idx == 4) return p4;
    return 1.0f;
}

// bijective XCD-aware remap, x-fastest within an XCD: blocks sharing (y,z)
// operand streams stay on one XCD. (total blocks % 8 == 0)
template<int NX, int NY, int NZ>
__device__ __forceinline__ void swzdec(int& x, int& y, int& z) {
    const int L = blockIdx.x + NX * (blockIdx.y + NY * blockIdx.z);
    constexpr int cpx = NX * NY * NZ / 8;
    const int s = (L & 7) * cpx + (L >> 3);
    x = s % NX;
    const int r = s / NX;
    y = r % NY;
    z = r / NY;
}
// variant: x-OUTER (y,z fastest) -- each XCD owns a contiguous x-range and
// sweeps all (y,z) for it. Used where x selects the big streamed operand.
template<int NX, int NY, int NZ>
__device__ __forceinline__ void swzdec_xo(int& x, int& y, int& z) {
    const int L = blockIdx.x + NX * (blockIdx.y + NY * blockIdx.z);
    constexpr int cpx = NX * NY * NZ / 8;
    const int s = (L & 7) * cpx + (L >> 3);
    x = s / (NY * NZ);
    const int r = s % (NY * NZ);
    y = r % NY;
    z = r / NY;
}

#define MFMA(a, b, c) __builtin_amdgcn_mfma_f32_32x32x16_bf16((a), (b), (c), 0, 0, 0)

// ---------------------------------------------------------------------------
// fp32 [R][256] -> fragment-major bf16: [tile][c(16)][lane(64)][8] so qkv MFMA
// loads are contiguous 1KiB wave-loads. x1 (150 tiles), x2 (150), w (24).
// Blocks >= 324 zero the accumulator region (replaces the memset dispatch).
// ---------------------------------------------------------------------------
__global__ __launch_bounds__(256) void frag_kernel(
    const float* __restrict__ x1, unsigned short* __restrict__ xh1,
    const float* __restrict__ x2, unsigned short* __restrict__ xh2,
    const float* __restrict__ w, unsigned short* __restrict__ wh,
    float* __restrict__ zbase, int zn4)
{
    int b = blockIdx.x;
    const int t = threadIdx.x;
    if (b >= 324) {
        const int i = (b - 324) * 256 + t;
        if (i < zn4) ((float4*)zbase)[i] = make_float4(0.f, 0.f, 0.f, 0.f);
        return;
    }
    const float* src; unsigned short* dh;
    if (b < 150)      { src = x1 + b * 8192; dh = xh1 + b * 8192; }
    else if (b < 300) { b -= 150; src = x2 + b * 8192; dh = xh2 + b * 8192; }
    else              { b -= 300; src = w + b * 8192; dh = wh + b * 8192; }
#pragma unroll
    for (int k = 0; k < 4; ++k) {
        const int f = k * 256 + t;            // 16B-chunk index, 1024 per tile
        const int c = f >> 6;
        const int rem = f & 63;
        const float* sp = src + (rem & 31) * 256 + c * 16 + (rem >> 5) * 8;
        const float4 a = *(const float4*)(sp);
        const float4 bb = *(const float4*)(sp + 4);
        const float vv[8] = {a.x, a.y, a.z, a.w, bb.x, bb.y, bb.z, bb.w};
        union { unsigned short s[8]; s8v v; } H;
#pragma unroll
        for (int j = 0; j < 8; ++j) H.s[j] = f2bf(vv[j]);
        *(s8v*)(dh + f * 8) = H.v;
    }
}

// ---------------------------------------------------------------------------
// QKV GEMM, plain bf16 MFMA on fragment-major inputs. Each wave: one x-tile
// (32 n) x 2 w-tiles (64 j). grid (75, 12, 2), x-outer XCD swizzle so each
// XCD reads its x-range once. Epilogue goes through a per-wave LDS transpose
// so all global writes are contiguous full-line regions (2KB bf16 / 4KB f32).
// ---------------------------------------------------------------------------
__global__ __launch_bounds__(128, 4) void qkv_mfma_kernel(
    const unsigned short* __restrict__ xhA, unsigned short* __restrict__ qbA,
    unsigned short* __restrict__ kbA, float* __restrict__ vcbA,
    const unsigned short* __restrict__ xhB, unsigned short* __restrict__ qbB,
    unsigned short* __restrict__ kbB, float* __restrict__ vcbB,
    const unsigned short* __restrict__ wh)
{
    __shared__ float tlbuf[2][32][33];
    int bx, by, bz;
    swzdec_xo<75, 12, 2>(bx, by, bz);
    const int sel = bz;
    const unsigned short* xh = sel ? xhB : xhA;
    unsigned short* qb = sel ? qbB : qbA;
    unsigned short* kb = sel ? kbB : kbA;
    float* vcb = sel ? vcbB : vcbA;
    const int lane = threadIdx.x & 63;
    const int wid = threadIdx.x >> 6;
    const int xtile = bx * 2 + wid;
    const unsigned short* xp = xh + (size_t)xtile * 8192 + lane * 8;
    const unsigned short* wp0 = wh + (size_t)(by * 2) * 8192 + lane * 8;
    const unsigned short* wp1 = wp0 + 8192;
    f32x16 acc0 = {}, acc1 = {};
#pragma unroll
    for (int c = 0; c < 16; ++c) {
        const s8v aH = *(const s8v*)(xp + c * 512);
        const s8v b0 = *(const s8v*)(wp0 + c * 512);
        const s8v b1 = *(const s8v*)(wp1 + c * 512);
        acc0 = MFMA(aH, b0, acc0);
        acc1 = MFMA(aH, b1, acc1);
    }
    const int lr = lane & 31, hi5 = lane >> 5;
    const int row = lane >> 1, ch = (lane & 1) * 16;
    float (*T)[33] = tlbuf[wid];
#pragma unroll
    for (int jj = 0; jj < 2; ++jj) {
        // stage this j-tile's C fragment into LDS (wave-private buffer;
        // compiler inserts the lgkmcnt waits for the ds write->read dep)
#pragma unroll
        for (int r = 0; r < 16; ++r) {
            const float v = jj ? acc1[r] : acc0[r];
            T[(r & 3) + 8 * (r >> 2) + 4 * hi5][lr] = v;
        }
        const int jt = by * 2 + jj, s = jt >> 3, h = jt & 7;
        const int n = xtile * 32 + row;
        if (s == 2) {
            float4* dst = (float4*)&vcb[(size_t)(h * N_TOK + n) * HD + ch];
#pragma unroll
            for (int k = 0; k < 4; ++k) {
                dst[k] = make_float4(T[row][ch + 4 * k + 0], T[row][ch + 4 * k + 1],
                                     T[row][ch + 4 * k + 2], T[row][ch + 4 * k + 3]);
            }
        } else {
            const float m = (s == 0) ? QSCALE : 1.0f;
            unsigned short* dst = (s == 0 ? qb : kb)
                                  + (size_t)(h * N_TOK + n) * HD + ch;
            union { unsigned short u[8]; s8v v; } o0, o1;
#pragma unroll
            for (int i = 0; i < 8; ++i) {
                o0.u[i] = f2bf(T[row][ch + i] * m);
                o1.u[i] = f2bf(T[row][ch + 8 + i] * m);
            }
            *(s8v*)dst = o0.v;
            *(s8v*)(dst + 8) = o1.v;
        }
    }
}

// ---------------------------------------------------------------------------
// Pass 1 (both fundamentals): S' = Q'.K^T via bf16 MFMA; cs[m] += sum_n 2^S'.
// Each wave owns TWO fixed K-tiles (64 m); packed f32 accumulate; 2-slot
// software pipeline. grid (25, 5, 16), XCD-swizzled, 192 thr.
// Overruns q buffer by <= 2 row-tiles -- layout pad rule covers it.
// ---------------------------------------------------------------------------
__global__ __launch_bounds__(192, 4) void cs_kernel(
    const unsigned short* __restrict__ qbA, const unsigned short* __restrict__ kbA,
    float* __restrict__ csA,
    const unsigned short* __restrict__ qbB, const unsigned short* __restrict__ kbB,
    float* __restrict__ csB)
{
    int bx, by, bz;
    swzdec<25, 5, 16>(bx, by, bz);
    const int sel = bz >> 3;
    const unsigned short* qb = sel ? qbB : qbA;
    const unsigned short* kb = sel ? kbB : kbA;
    float* cs = sel ? csB : csA;
    const int lane = threadIdx.x & 63;
    const int wid = threadIdx.x >> 6;
    const int h = bz & 7;
    const int m0 = bx * 192 + wid * 64;       // two 32-tiles: m0, m0+32
    const int lr = lane & 31, hi5 = lane >> 5;
    const int hbase = h * N_TOK;
    const unsigned short* kp = kb + (hbase + m0 + lr) * HD + 8 * hi5;
    const s8v bK0 = *(const s8v*)(kp);
    const s8v bK1 = *(const s8v*)(kp + 16);
    const s8v bK2 = *(const s8v*)(kp + 32 * HD);
    const s8v bK3 = *(const s8v*)(kp + 32 * HD + 16);
    const unsigned short* qp = qb + (hbase + by * 960 + lr) * HD + 8 * hi5;
    s8v qa0[2], qa1[2];
    qa0[0] = *(const s8v*)(qp);
    qa1[0] = *(const s8v*)(qp + 16);
    qp += 32 * HD;
    qa0[1] = *(const s8v*)(qp);
    qa1[1] = *(const s8v*)(qp + 16);
    qp += 32 * HD;
    f32x2 cA0 = {0.f, 0.f}, cA1 = {0.f, 0.f};
    f32x2 cB0 = {0.f, 0.f}, cB1 = {0.f, 0.f};
#pragma unroll 2
    for (int it = 0; it < 30; ++it) {
        const int c = it & 1;
        f32x16 accA = {}, accB = {};
        accA = MFMA(qa0[c], bK0, accA);
        accB = MFMA(qa0[c], bK2, accB);
        accA = MFMA(qa1[c], bK1, accA);
        accB = MFMA(qa1[c], bK3, accB);
#pragma unroll
        for (int k = 0; k < 8; ++k) {
            f32x2 eA, eB;
            eA.x = EXP2F(accA[2 * k]);
            eA.y = EXP2F(accA[2 * k + 1]);
            eB.x = EXP2F(accB[2 * k]);
            eB.y = EXP2F(accB[2 * k + 1]);
            if (k & 1) { cA1 += eA; cB1 += eB; }
            else       { cA0 += eA; cB0 += eB; }
        }
        // refill slot c with tile it+2 (unconditional; pad rule covers end)
        qa0[c] = *(const s8v*)(qp);
        qa1[c] = *(const s8v*)(qp + 16);
        qp += 32 * HD;
    }
    float cA = cA0.x + cA0.y + cA1.x + cA1.y;
    float cB = cB0.x + cB0.y + cB1.x + cB1.y;
    cA += __shfl_xor(cA, 32);
    cB += __shfl_xor(cB, 32);
    if (lane < 32) {
        atomicAdd(&cs[hbase + m0 + lane], cA);
        atomicAdd(&cs[hbase + m0 + 32 + lane], cB);
    }
}

// ---------------------------------------------------------------------------
// vc fp32 [h][4800][32] + inline pos + u=1/cs -> fragment-major bf16 vfrag
// [h][mtile][b][lane][8]. Both fundamentals: grid (150, 16), 256 threads.
// ---------------------------------------------------------------------------
__global__ __launch_bounds__(256) void vfrag_kernel(
    const float* __restrict__ vcA, const float* __restrict__ csA,
    unsigned short* __restrict__ vfA,
    const float* __restrict__ vcB, const float* __restrict__ csB,
    unsigned short* __restrict__ vfB)
{
    const int sel = blockIdx.y >> 3;
    const float* vc = sel ? vcB : vcA;
    const float* cs = sel ? csB : csA;
    unsigned short* vf = sel ? vfB : vfA;
    __shared__ float vl[32][33];
    __shared__ float ul[32];
    const int mt = blockIdx.x;
    const int h = blockIdx.y & 7;
    const int t = threadIdx.x;
    const int m0 = mt * 32;
    const float* vcbase = vc + (size_t)(h * N_TOK + m0) * HD;
    for (int e = t; e < 32 * HD; e += 256) vl[e >> 5][e & 31] = vcbase[e];
    if (t < 32) ul[t] = 1.0f / cs[(size_t)h * N_TOK + m0 + t];
    __syncthreads();
    const int b = t >> 6, lane = t & 63;
    const int hi5 = lane >> 5, lr = lane & 31;
    const int d = (b >> 1) * 32 + lr;       // 0..63 (>=38 zero pad)
    const int mb = (b & 1) * 16 + hi5 * 8;  // k-offset within tile
    union { unsigned short s[8]; s8v v; } pk;
#pragma unroll
    for (int j = 0; j < 8; ++j) {
        const int mo = mb + j;
        float v;
        if (d < 32)      v = vl[mo][d];
        else if (d < 38) v = posv(m0 + mo, d - 32);
        else             v = 0.0f;
        pk.s[j] = f2bf(v * ul[mo]);
    }
    *(s8v*)(vf + ((size_t)(h * NTILES + mt) * 4 + b) * 512 + lane * 8) = pk.v;
}

// ---------------------------------------------------------------------------
// Pass 2 (both fundamentals): S'^T = K.Q'^T; e = 2^S'; rs += e (packed f32);
// P' = e*e packed in-register; T' += P'.vfrag via MFMA. Each wave computes
// TWO n-tiles (64 rows) against one shared K/V stream: 6 loads serve 2 tiles,
// and all 4 S-MFMAs issue before the first exp so tile B's scores complete
// in the matrix pipe under tile A's exp/pack (in-wave pipelining).
// 3 m-chunks with separate bf16 T partials (lane-pair packed plain stores).
// grid (25, 3, 16) XCD-swizzled, 192 thr. Overruns <= 1 tile -- pad rule.
// ---------------------------------------------------------------------------
__global__ __launch_bounds__(192, 3) void tprime_mfma_kernel(
    const unsigned short* __restrict__ qbA, const unsigned short* __restrict__ kbA,
    const unsigned short* __restrict__ vfA, float* __restrict__ rsA,
    unsigned short* __restrict__ TA0, unsigned short* __restrict__ TA1,
    unsigned short* __restrict__ TA2,
    const unsigned short* __restrict__ qbB, const unsigned short* __restrict__ kbB,
    const unsigned short* __restrict__ vfB, float* __restrict__ rsB,
    unsigned short* __restrict__ TB0, unsigned short* __restrict__ TB1,
    unsigned short* __restrict__ TB2)
{
    int bx, by, bz;
    swzdec<25, MCHUNK, 16>(bx, by, bz);
    const int sel = bz >> 3;
    const unsigned short* qb = sel ? qbB : qbA;
    const unsigned short* kb = sel ? kbB : kbA;
    const unsigned short* vf = sel ? vfB : vfA;
    float* rs = sel ? rsB : rsA;
    unsigned short* T = sel ? (by == 0 ? TB0 : (by == 1 ? TB1 : TB2))
                            : (by == 0 ? TA0 : (by == 1 ? TA1 : TA2));
    const int lane = threadIdx.x & 63;
    const int wid = threadIdx.x >> 6;
    const int h = bz & 7;
    const int n0 = bx * 192 + wid * 64;       // two n-tiles: n0, n0+32
    const int lr = lane & 31, hi5 = lane >> 5;
    const int hbase = h * N_TOK;
    // Q as B operand for both n-tiles (hoisted across the m-loop)
    const unsigned short* qp = qb + (hbase + n0 + lr) * HD + 8 * hi5;
    const s8v bQ0 = *(const s8v*)(qp);
    const s8v bQ1 = *(const s8v*)(qp + 16);
    const s8v bQ2 = *(const s8v*)(qp + 32 * HD);
    const s8v bQ3 = *(const s8v*)(qp + 32 * HD + 16);
    f32x16 t0A = {}, t1A = {}, t0B = {}, t1B = {};
    const int mt0 = by * 50;
    const unsigned short* kp = kb + (hbase + mt0 * 32 + lr) * HD + 8 * hi5;
    const unsigned short* vp = vf + (size_t)(h * NTILES + mt0) * FRAG + lane * 8;
    s8v a0 = *(const s8v*)(kp);
    s8v a1 = *(const s8v*)(kp + 16);
    s8v v00 = *(const s8v*)(vp);
    s8v v01 = *(const s8v*)(vp + 512);
    s8v v10 = *(const s8v*)(vp + 1024);
    s8v v11 = *(const s8v*)(vp + 1536);
    f32x2 rsA0 = {0.f, 0.f}, rsA1 = {0.f, 0.f};
    f32x2 rsB0 = {0.f, 0.f}, rsB1 = {0.f, 0.f};
#pragma unroll 2
    for (int it = 0; it < 50; ++it) {
        // prefetch next tile's K and V (6 coalesced 1KiB loads serve 2 n-tiles)
        kp += 32 * HD; vp += FRAG;
        const s8v na0 = *(const s8v*)(kp);
        const s8v na1 = *(const s8v*)(kp + 16);
        const s8v nv00 = *(const s8v*)(vp);
        const s8v nv01 = *(const s8v*)(vp + 512);
        const s8v nv10 = *(const s8v*)(vp + 1024);
        const s8v nv11 = *(const s8v*)(vp + 1536);
        // all 4 S-MFMAs first: tile B's scores mature under tile A's exp/pack
        f32x16 sA = {}, sB = {};
        sA = MFMA(a0, bQ0, sA);
        sB = MFMA(a0, bQ2, sB);
        sA = MFMA(a1, bQ1, sA);
        sB = MFMA(a1, bQ3, sB);
        // ---- tile A: exp, pack, PV ----
        {
            f32x2 p2[8];
#pragma unroll
            for (int k = 0; k < 8; ++k) {
                f32x2 e2;
                e2.x = EXP2F(sA[2 * k]);
                e2.y = EXP2F(sA[2 * k + 1]);
                if (k & 1) rsA1 += e2; else rsA0 += e2;
                p2[k] = e2 * e2;
            }
            const int L0 = cvtpk(p2[0].x, p2[0].y), L1 = cvtpk(p2[1].x, p2[1].y);
            const int H0 = cvtpk(p2[2].x, p2[2].y), H1 = cvtpk(p2[3].x, p2[3].y);
            const int L2 = cvtpk(p2[4].x, p2[4].y), L3 = cvtpk(p2[5].x, p2[5].y);
            const int H2 = cvtpk(p2[6].x, p2[6].y), H3 = cvtpk(p2[7].x, p2[7].y);
            const i2v s0 = __builtin_amdgcn_permlane32_swap(L0, H0, false, false);
            const i2v s1 = __builtin_amdgcn_permlane32_swap(L1, H1, false, false);
            const i2v s2 = __builtin_amdgcn_permlane32_swap(L2, H2, false, false);
            const i2v s3 = __builtin_amdgcn_permlane32_swap(L3, H3, false, false);
            const s8v pa0 = mk_s8(s0[0], s1[0], s0[1], s1[1]);   // k = 0..15
            const s8v pa1 = mk_s8(s2[0], s3[0], s2[1], s3[1]);   // k = 16..31
            __builtin_amdgcn_s_setprio(1);
            t0A = MFMA(pa0, v00, t0A);
            t0A = MFMA(pa1, v01, t0A);
            t1A = MFMA(pa0, v10, t1A);
            t1A = MFMA(pa1, v11, t1A);
            __builtin_amdgcn_s_setprio(0);
        }
        // ---- tile B: exp, pack, PV ----
        {
            f32x2 p2[8];
#pragma unroll
            for (int k = 0; k < 8; ++k) {
                f32x2 e2;
                e2.x = EXP2F(sB[2 * k]);
                e2.y = EXP2F(sB[2 * k + 1]);
                if (k & 1) rsB1 += e2; else rsB0 += e2;
                p2[k] = e2 * e2;
            }
            const int L0 = cvtpk(p2[0].x, p2[0].y), L1 = cvtpk(p2[1].x, p2[1].y);
            const int H0 = cvtpk(p2[2].x, p2[2].y), H1 = cvtpk(p2[3].x, p2[3].y);
            const int L2 = cvtpk(p2[4].x, p2[4].y), L3 = cvtpk(p2[5].x, p2[5].y);
            const int H2 = cvtpk(p2[6].x, p2[6].y), H3 = cvtpk(p2[7].x, p2[7].y);
            const i2v s0 = __builtin_amdgcn_permlane32_swap(L0, H0, false, false);
            const i2v s1 = __builtin_amdgcn_permlane32_swap(L1, H1, false, false);
            const i2v s2 = __builtin_amdgcn_permlane32_swap(L2, H2, false, false);
            const i2v s3 = __builtin_amdgcn_permlane32_swap(L3, H3, false, false);
            const s8v pa0 = mk_s8(s0[0], s1[0], s0[1], s1[1]);
            const s8v pa1 = mk_s8(s2[0], s3[0], s2[1], s3[1]);
            __builtin_amdgcn_s_setprio(1);
            t0B = MFMA(pa0, v00, t0B);
            t0B = MFMA(pa1, v01, t0B);
            t1B = MFMA(pa0, v10, t1B);
            t1B = MFMA(pa1, v11, t1B);
            __builtin_amdgcn_s_setprio(0);
        }
        a0 = na0; a1 = na1;
        v00 = nv00; v01 = nv01; v10 = nv10; v11 = nv11;
    }
    float rA = rsA0.x + rsA0.y + rsA1.x + rsA1.y;
    float rB = rsB0.x + rsB0.y + rsB1.x + rsB1.y;
    rA += __shfl_xor(rA, 32);
    rB += __shfl_xor(rB, 32);
    if (lane < 32) {
        atomicAdd(&rs[hbase + n0 + lane], rA);
        atomicAdd(&rs[hbase + n0 + 32 + lane], rB);
    }
    // T stored bf16: pair d=(2j,2j+1) packed via lane-xor-1 exchange,
    // even lanes store one dword (row layout [n][DP] bf16, DP/2 dwords/row)
    unsigned int* Tw = (unsigned int*)T;
#pragma unroll
    for (int r = 0; r < 16; ++r) {
        const int crow = (r & 3) + 8 * (r >> 2) + 4 * hi5;
        const int nA = n0 + crow, nB = n0 + 32 + crow;
        const float pA0 = __shfl_xor(t0A[r], 1);
        const float pA1 = __shfl_xor(t1A[r], 1);
        const float pB0 = __shfl_xor(t0B[r], 1);
        const float pB1 = __shfl_xor(t1B[r], 1);
        if (!(lr & 1)) {
            Tw[(size_t)(hbase + nA) * (DP / 2) + (lr >> 1)] =
                (unsigned int)cvtpk(t0A[r], pA0);
            Tw[(size_t)(hbase + nB) * (DP / 2) + (lr >> 1)] =
                (unsigned int)cvtpk(t0B[r], pB0);
            if (lr < 8) {
                Tw[(size_t)(hbase + nA) * (DP / 2) + 16 + (lr >> 1)] =
                    (unsigned int)cvtpk(t1A[r], pA1);
                Tw[(size_t)(hbase + nB) * (DP / 2) + 16 + (lr >> 1)] =
                    (unsigned int)cvtpk(t1B[r], pB1);
            }
        }
    }
}

// ---------------------------------------------------------------------------
// f[h,c,d] = sum_n (vc[n,c]/rs[n]) * (T0'+T1'+T2')[n,d] per 64-row chunk.
// T partials are bf16. vc cols 32..37 = inline pos. grid (16, 75).
// ---------------------------------------------------------------------------
__global__ __launch_bounds__(256) void fgemm_kernel(
    const float* __restrict__ VCA, const float* __restrict__ rsA,
    const unsigned short* __restrict__ TA0, const unsigned short* __restrict__ TA1,
    const unsigned short* __restrict__ TA2, float* __restrict__ fA,
    const float* __restrict__ VCB, const float* __restrict__ rsB,
    const unsigned short* __restrict__ TB0, const unsigned short* __restrict__ TB1,
    const unsigned short* __restrict__ TB2, float* __restrict__ fB)
{
    const int sel = blockIdx.x >> 3;
    const float* VC = sel ? VCB : VCA;
    const float* rs = sel ? rsB : rsA;
    const unsigned short* Ta = sel ? TB0 : TA0;
    const unsigned short* Tb = sel ? TB1 : TA1;
    const unsigned short* Tc = sel ? TB2 : TA2;
    float* f = sel ? fB : fA;
    __shared__ __align__(16) float wvcl[64 * DP];
    __shared__ __align__(16) float tl[64 * DP];
    __shared__ float wl[64];
    const int h = blockIdx.x & 7, n0 = blockIdx.y * 64;
    const int t = threadIdx.x;
    if (t < 64) wl[t] = 1.0f / rs[(size_t)h * N_TOK + n0 + t];
    __syncthreads();
    const float* vcbase = VC + (size_t)(h * N_TOK + n0) * HD;
    const ushort4* ta4 = (const ushort4*)(Ta + (size_t)(h * N_TOK + n0) * DP);
    const ushort4* tb4 = (const ushort4*)(Tb + (size_t)(h * N_TOK + n0) * DP);
    const ushort4* tc4 = (const ushort4*)(Tc + (size_t)(h * N_TOK + n0) * DP);
    for (int e4 = t; e4 < 64 * DP / 4; e4 += 256) {
        const ushort4 a4 = ta4[e4];
        const ushort4 b4 = tb4[e4];
        const ushort4 c4 = tc4[e4];
        tl[e4 * 4 + 0] = bf2f(a4.x) + bf2f(b4.x) + bf2f(c4.x);
        tl[e4 * 4 + 1] = bf2f(a4.y) + bf2f(b4.y) + bf2f(c4.y);
        tl[e4 * 4 + 2] = bf2f(a4.z) + bf2f(b4.z) + bf2f(c4.z);
        tl[e4 * 4 + 3] = bf2f(a4.w) + bf2f(b4.w) + bf2f(c4.w);
    }
    for (int e = t; e < 64 * DP; e += 256) {
        const int row = e / DP, c = e - row * DP;
        float v;
        if (c < 32)      v = vcbase[row * HD + c];
        else if (c < 38) v = posv(n0 + row, c - 32);
        else             v = 0.0f;
        wvcl[e] = v * wl[row];
    }
    __syncthreads();
    for (int p = t; p < DD * DD; p += 256) {
        const int c = p / DD, d = p % DD;
        float s = 0.f;
#pragma unroll 8
        for (int n = 0; n < 64; ++n) s += wvcl[n * DP + c] * tl[n * DP + d];
        atomicAdd(&f[(size_t)(h * DD + c) * DP + d], s);
    }
}

// ---------------------------------------------------------------------------
// out[d,e] = sum_j f[j,d] * proj_w[e,j] + proj_b[e]. Both fundamentals:
// grid (38, 2); y=0 -> f1 -> out+DD*256, y=1 -> f2 -> out.
// ---------------------------------------------------------------------------
__global__ __launch_bounds__(256) void out_kernel(
    const float* __restrict__ f1, const float* __restrict__ f2,
    const float* __restrict__ pw, const float* __restrict__ pb,
    float* __restrict__ out)
{
    const int sel = blockIdx.y;
    const float* f = sel ? f2 : f1;
    float* dst = sel ? out : (out + DD * 256);
    __shared__ __align__(16) float flds[304];
    const int d = blockIdx.x, t = threadIdx.x;
    for (int j = t; j < 304; j += 256) flds[j] = f[(size_t)j * DP + d];
    __syncthreads();
    float acc = pb[t];
    const float* pwrow = pw + (size_t)t * 304;
#pragma unroll 4
    for (int j = 0; j < 304; j += 4) {
        const float4 p4 = *(const float4*)&pwrow[j];
        const float4 f4 = *(const float4*)&flds[j];
        acc += p4.x * f4.x + p4.y * f4.y + p4.z * f4.z + p4.w * f4.w;
    }
    dst[(size_t)d * 256 + t] = acc;
}

extern "C" void kernel_launch(void* const* d_in, const int* in_sizes, int n_in,
                              void* d_out, int out_size, void* d_ws, size_t ws_size,
                              hipStream_t stream)
{
    const float* x1 = (const float*)d_in[0];
    const float* x2 = (const float*)d_in[1];
    const float* qkv_w = (const float*)d_in[2];
    const float* proj_w = (const float*)d_in[3];
    const float* proj_b = (const float*)d_in[4];
    float* out = (float*)d_out;

    const size_t QSZ = (size_t)NH * N_TOK * HD;          // 1,228,800
    const size_t VSZ = (size_t)NH * N_TOK * DP;          // 1,536,000
    const size_t SSZ = (size_t)NH * N_TOK;               //    38,400
    const size_t FSZ = (size_t)NH * DD * DP;             //    12,160
    const size_t XSZ = (size_t)N_TOK * 256;              // 1,228,800
    const size_t WSZ = (size_t)768 * 256;                //   196,608
    const size_t VTSZ = (size_t)NH * NTILES * FRAG;      // 2,457,600

    // fp32 region
    float* vc1 = (float*)d_ws;          // [h][4800][32]
    float* vc2 = vc1 + QSZ;
    float* rs1 = vc2 + QSZ;   // zeroed region starts here
    float* cs1 = rs1 + SSZ;
    float* rs2 = cs1 + SSZ;
    float* cs2 = rs2 + SSZ;
    float* f1 = cs2 + SSZ;
    float* f2 = f1 + FSZ;     // zeroed region ends at f2 + FSZ
    // bf16 region -- ORDER MATTERS: unconditional prefetches overrun each
    // buffer by <= 2 tiles into the next allocated buffer.
    unsigned short* xh1 = (unsigned short*)(f2 + FSZ);
    unsigned short* xh2 = xh1 + XSZ;
    unsigned short* wh = xh2 + XSZ;
    unsigned short* qb1 = wh + WSZ;
    unsigned short* kb1 = qb1 + QSZ;    // qb1 overrun -> kb1
    unsigned short* qb2 = kb1 + QSZ;    // kb1 overrun -> qb2
    unsigned short* kb2 = qb2 + QSZ;    // qb2 overrun -> kb2
    unsigned short* vf1 = kb2 + QSZ;    // kb2 overrun -> vf1
    unsigned short* vf2 = vf1 + VTSZ;   // vf1 overrun -> vf2
    unsigned short* T1a = vf2 + VTSZ;   // vf2 overrun -> T1a (values unused)
    unsigned short* T1b = T1a + VSZ;    // T partials (bf16), fully overwritten
    unsigned short* T1c = T1b + VSZ;
    unsigned short* T2a = T1c + VSZ;
    unsigned short* T2b = T2a + VSZ;
    unsigned short* T2c = T2b + VSZ;

    const int zn4 = (int)((4 * SSZ + 2 * FSZ) / 4);   // float4 count to zero

    frag_kernel<<<324 + 174, 256, 0, stream>>>(x1, xh1, x2, xh2, qkv_w, wh,
                                               rs1, zn4);

    qkv_mfma_kernel<<<dim3(75, 12, 2), 128, 0, stream>>>(
        xh1, qb1, kb1, vc1, xh2, qb2, kb2, vc2, wh);

    // fundamental_1 = f(q2, k1, vc1); fundamental_2 = f(q1, k2, vc2)
    cs_kernel<<<dim3(25, 5, 16), 192, 0, stream>>>(qb2, kb1, cs1,
                                                   qb1, kb2, cs2);
    vfrag_kernel<<<dim3(150, 16), 256, 0, stream>>>(vc1, cs1, vf1,
                                                    vc2, cs2, vf2);
    tprime_mfma_kernel<<<dim3(25, MCHUNK, 16), 192, 0, stream>>>(
        qb2, kb1, vf1, rs1, T1a, T1b, T1c,
        qb1, kb2, vf2, rs2, T2a, T2b, T2c);
    fgemm_kernel<<<dim3(16, 75), 256, 0, stream>>>(
        vc1, rs1, T1a, T1b, T1c, f1,
        vc2, rs2, T2a, T2b, T2c, f2);
    out_kernel<<<dim3(38, 2), 256, 0, stream>>>(f1, f2, proj_w, proj_b, out);
}

// Round 12
// 211.722 us; speedup vs baseline: 1.5806x; 1.5806x over previous
//
#include <hip/hip_runtime.h>
#include <stdint.h>
#include <math.h>

#define N_TOK 4800
#define NH 8
#define HD 32
#define DP 40          // T' padded leading dim (D=38 -> 40)
#define DD 38
#define NTILES 150     // 32-wide m tiles
#define MCHUNK 3       // m-chunks in tprime (50 tiles each)
#define FRAG 2048      // shorts per (h,mtile) V fragment: 4 blocks x 64 lanes x 8
#define SCALE 0.17677669529663687f            // 32^-0.5
#define QSCALE (0.17677669529663687f * 1.4426950408889634f)  // SCALE*log2(e)

typedef float f32x16 __attribute__((ext_vector_type(16)));
typedef float f32x2 __attribute__((ext_vector_type(2)));
typedef short s8v __attribute__((ext_vector_type(8)));
typedef int i2v __attribute__((ext_vector_type(2)));

#if __has_builtin(__builtin_amdgcn_exp2f)
#define EXP2F(x) __builtin_amdgcn_exp2f(x)
#else
#define EXP2F(x) exp2f(x)
#endif

__device__ __forceinline__ unsigned short f2bf(float x) {
    union { float f; uint32_t u; } v; v.f = x;
    uint32_t r = v.u + 0x7FFFu + ((v.u >> 16) & 1u);
    return (unsigned short)(r >> 16);
}
__device__ __forceinline__ float bf2f(unsigned short h) {
    union { uint32_t u; float f; } v; v.u = ((uint32_t)h) << 16;
    return v.f;
}
__device__ __forceinline__ int cvtpk(float lo, float hi) {
    int r;
    asm("v_cvt_pk_bf16_f32 %0, %1, %2" : "=v"(r) : "v"(lo), "v"(hi));
    return r;
}
__device__ __forceinline__ s8v mk_s8(int a, int b, int c, int d) {
    union { int i[4]; s8v s; } u;
    u.i[0] = a; u.i[1] = b; u.i[2] = c; u.i[3] = d;
    return u.s;
}
// positional encoding component idx (0..5) for token m
__device__ __forceinline__ float posv(int m, int idx) {
    const int rrow = m / 80, rcol = m % 80;
    const float y = -1.0f + (float)rrow * (2.0f / 59.0f);
    const float x = -1.0f + (float)rcol * (2.0f / 79.0f);
    const float p3 = y * (240.0f / 517.0f);
    const float p4 = x * (360.0f / 517.0f);
    if (idx == 0) return p3 * p3;
    if (idx == 1) return p4 * p4;
    if (idx == 2) return p3 * p4;
    if (idx == 3) return p3;
    if (idx == 4) return p4;
    return 1.0f;
}

// bijective XCD-aware remap, x-fastest within an XCD: blocks sharing (y,z)
// operand streams stay on one XCD. (total blocks % 8 == 0)
template<int NX, int NY, int NZ>
__device__ __forceinline__ void swzdec(int& x, int& y, int& z) {
    const int L = blockIdx.x + NX * (blockIdx.y + NY * blockIdx.z);
    constexpr int cpx = NX * NY * NZ / 8;
    const int s = (L & 7) * cpx + (L >> 3);
    x = s % NX;
    const int r = s / NX;
    y = r % NY;
    z = r / NY;
}
// variant: x-OUTER (y,z fastest) -- each XCD owns a contiguous x-range and
// sweeps all (y,z) for it. Used where x selects the big streamed operand.
template<int NX, int NY, int NZ>
__device__ __forceinline__ void swzdec_xo(int& x, int& y, int& z) {
    const int L = blockIdx.x + NX * (blockIdx.y + NY * blockIdx.z);
    constexpr int cpx = NX * NY * NZ / 8;
    const int s = (L & 7) * cpx + (L >> 3);
    x = s / (NY * NZ);
    const int r = s % (NY * NZ);
    y = r % NY;
    z = r / NY;
}

#define MFMA(a, b, c) __builtin_amdgcn_mfma_f32_32x32x16_bf16((a), (b), (c), 0, 0, 0)

// ---------------------------------------------------------------------------
// fp32 [R][256] -> fragment-major bf16: [tile][c(16)][lane(64)][8] so qkv MFMA
// loads are contiguous 1KiB wave-loads. x1 (150 tiles), x2 (150), w (24).
// Blocks >= 324 zero the accumulator region (replaces the memset dispatch).
// ---------------------------------------------------------------------------
__global__ __launch_bounds__(256) void frag_kernel(
    const float* __restrict__ x1, unsigned short* __restrict__ xh1,
    const float* __restrict__ x2, unsigned short* __restrict__ xh2,
    const float* __restrict__ w, unsigned short* __restrict__ wh,
    float* __restrict__ zbase, int zn4)
{
    int b = blockIdx.x;
    const int t = threadIdx.x;
    if (b >= 324) {
        const int i = (b - 324) * 256 + t;
        if (i < zn4) ((float4*)zbase)[i] = make_float4(0.f, 0.f, 0.f, 0.f);
        return;
    }
    const float* src; unsigned short* dh;
    if (b < 150)      { src = x1 + b * 8192; dh = xh1 + b * 8192; }
    else if (b < 300) { b -= 150; src = x2 + b * 8192; dh = xh2 + b * 8192; }
    else              { b -= 300; src = w + b * 8192; dh = wh + b * 8192; }
#pragma unroll
    for (int k = 0; k < 4; ++k) {
        const int f = k * 256 + t;            // 16B-chunk index, 1024 per tile
        const int c = f >> 6;
        const int rem = f & 63;
        const float* sp = src + (rem & 31) * 256 + c * 16 + (rem >> 5) * 8;
        const float4 a = *(const float4*)(sp);
        const float4 bb = *(const float4*)(sp + 4);
        const float vv[8] = {a.x, a.y, a.z, a.w, bb.x, bb.y, bb.z, bb.w};
        union { unsigned short s[8]; s8v v; } H;
#pragma unroll
        for (int j = 0; j < 8; ++j) H.s[j] = f2bf(vv[j]);
        *(s8v*)(dh + f * 8) = H.v;
    }
}

// ---------------------------------------------------------------------------
// QKV GEMM, plain bf16 MFMA on fragment-major inputs. Each wave: one x-tile
// (32 n) x 2 w-tiles (64 j). grid (75, 12, 2), x-outer XCD swizzle so each
// XCD reads its x-range once. Epilogue goes through a per-wave LDS transpose
// so all global writes are contiguous full-line regions (2KB bf16 / 4KB f32).
// ---------------------------------------------------------------------------
__global__ __launch_bounds__(128, 4) void qkv_mfma_kernel(
    const unsigned short* __restrict__ xhA, unsigned short* __restrict__ qbA,
    unsigned short* __restrict__ kbA, float* __restrict__ vcbA,
    const unsigned short* __restrict__ xhB, unsigned short* __restrict__ qbB,
    unsigned short* __restrict__ kbB, float* __restrict__ vcbB,
    const unsigned short* __restrict__ wh)
{
    __shared__ float tlbuf[2][32][33];
    int bx, by, bz;
    swzdec_xo<75, 12, 2>(bx, by, bz);
    const int sel = bz;
    const unsigned short* xh = sel ? xhB : xhA;
    unsigned short* qb = sel ? qbB : qbA;
    unsigned short* kb = sel ? kbB : kbA;
    float* vcb = sel ? vcbB : vcbA;
    const int lane = threadIdx.x & 63;
    const int wid = threadIdx.x >> 6;
    const int xtile = bx * 2 + wid;
    const unsigned short* xp = xh + (size_t)xtile * 8192 + lane * 8;
    const unsigned short* wp0 = wh + (size_t)(by * 2) * 8192 + lane * 8;
    const unsigned short* wp1 = wp0 + 8192;
    f32x16 acc0 = {}, acc1 = {};
#pragma unroll
    for (int c = 0; c < 16; ++c) {
        const s8v aH = *(const s8v*)(xp + c * 512);
        const s8v b0 = *(const s8v*)(wp0 + c * 512);
        const s8v b1 = *(const s8v*)(wp1 + c * 512);
        acc0 = MFMA(aH, b0, acc0);
        acc1 = MFMA(aH, b1, acc1);
    }
    const int lr = lane & 31, hi5 = lane >> 5;
    const int row = lane >> 1, ch = (lane & 1) * 16;
    float (*T)[33] = tlbuf[wid];
#pragma unroll
    for (int jj = 0; jj < 2; ++jj) {
        // stage this j-tile's C fragment into LDS (wave-private buffer;
        // compiler inserts the lgkmcnt waits for the ds write->read dep)
#pragma unroll
        for (int r = 0; r < 16; ++r) {
            const float v = jj ? acc1[r] : acc0[r];
            T[(r & 3) + 8 * (r >> 2) + 4 * hi5][lr] = v;
        }
        const int jt = by * 2 + jj, s = jt >> 3, h = jt & 7;
        const int n = xtile * 32 + row;
        if (s == 2) {
            float4* dst = (float4*)&vcb[(size_t)(h * N_TOK + n) * HD + ch];
#pragma unroll
            for (int k = 0; k < 4; ++k) {
                dst[k] = make_float4(T[row][ch + 4 * k + 0], T[row][ch + 4 * k + 1],
                                     T[row][ch + 4 * k + 2], T[row][ch + 4 * k + 3]);
            }
        } else {
            const float m = (s == 0) ? QSCALE : 1.0f;
            unsigned short* dst = (s == 0 ? qb : kb)
                                  + (size_t)(h * N_TOK + n) * HD + ch;
            union { unsigned short u[8]; s8v v; } o0, o1;
#pragma unroll
            for (int i = 0; i < 8; ++i) {
                o0.u[i] = f2bf(T[row][ch + i] * m);
                o1.u[i] = f2bf(T[row][ch + 8 + i] * m);
            }
            *(s8v*)dst = o0.v;
            *(s8v*)(dst + 8) = o1.v;
        }
    }
}

// ---------------------------------------------------------------------------
// Pass 1 (both fundamentals): S' = Q'.K^T via bf16 MFMA; cs[m] += sum_n 2^S'.
// Each wave owns TWO fixed K-tiles (64 m); packed f32 accumulate; 2-slot
// software pipeline (compute slot c, then refill slot c with tile it+2) for
// ~2-iteration load-latency cover. grid (25, 5, 16), XCD-swizzled, 192 thr.
// Overruns q buffer by <= 2 row-tiles -- layout pad rule covers it.
// ---------------------------------------------------------------------------
__global__ __launch_bounds__(192, 4) void cs_kernel(
    const unsigned short* __restrict__ qbA, const unsigned short* __restrict__ kbA,
    float* __restrict__ csA,
    const unsigned short* __restrict__ qbB, const unsigned short* __restrict__ kbB,
    float* __restrict__ csB)
{
    int bx, by, bz;
    swzdec<25, 5, 16>(bx, by, bz);
    const int sel = bz >> 3;
    const unsigned short* qb = sel ? qbB : qbA;
    const unsigned short* kb = sel ? kbB : kbA;
    float* cs = sel ? csB : csA;
    const int lane = threadIdx.x & 63;
    const int wid = threadIdx.x >> 6;
    const int h = bz & 7;
    const int m0 = bx * 192 + wid * 64;       // two 32-tiles: m0, m0+32
    const int lr = lane & 31, hi5 = lane >> 5;
    const int hbase = h * N_TOK;
    const unsigned short* kp = kb + (hbase + m0 + lr) * HD + 8 * hi5;
    const s8v bK0 = *(const s8v*)(kp);
    const s8v bK1 = *(const s8v*)(kp + 16);
    const s8v bK2 = *(const s8v*)(kp + 32 * HD);
    const s8v bK3 = *(const s8v*)(kp + 32 * HD + 16);
    const unsigned short* qp = qb + (hbase + by * 960 + lr) * HD + 8 * hi5;
    s8v qa0[2], qa1[2];
    qa0[0] = *(const s8v*)(qp);
    qa1[0] = *(const s8v*)(qp + 16);
    qp += 32 * HD;
    qa0[1] = *(const s8v*)(qp);
    qa1[1] = *(const s8v*)(qp + 16);
    qp += 32 * HD;
    f32x2 cA0 = {0.f, 0.f}, cA1 = {0.f, 0.f};
    f32x2 cB0 = {0.f, 0.f}, cB1 = {0.f, 0.f};
#pragma unroll 2
    for (int it = 0; it < 30; ++it) {
        const int c = it & 1;
        f32x16 accA = {}, accB = {};
        accA = MFMA(qa0[c], bK0, accA);
        accB = MFMA(qa0[c], bK2, accB);
        accA = MFMA(qa1[c], bK1, accA);
        accB = MFMA(qa1[c], bK3, accB);
#pragma unroll
        for (int k = 0; k < 8; ++k) {
            f32x2 eA, eB;
            eA.x = EXP2F(accA[2 * k]);
            eA.y = EXP2F(accA[2 * k + 1]);
            eB.x = EXP2F(accB[2 * k]);
            eB.y = EXP2F(accB[2 * k + 1]);
            if (k & 1) { cA1 += eA; cB1 += eB; }
            else       { cA0 += eA; cB0 += eB; }
        }
        // refill slot c with tile it+2 (unconditional; pad rule covers end)
        qa0[c] = *(const s8v*)(qp);
        qa1[c] = *(const s8v*)(qp + 16);
        qp += 32 * HD;
    }
    float cA = cA0.x + cA0.y + cA1.x + cA1.y;
    float cB = cB0.x + cB0.y + cB1.x + cB1.y;
    cA += __shfl_xor(cA, 32);
    cB += __shfl_xor(cB, 32);
    if (lane < 32) {
        atomicAdd(&cs[hbase + m0 + lane], cA);
        atomicAdd(&cs[hbase + m0 + 32 + lane], cB);
    }
}

// ---------------------------------------------------------------------------
// vc fp32 [h][4800][32] + inline pos + u=1/cs -> fragment-major bf16 vfrag
// [h][mtile][b][lane][8]. Both fundamentals: grid (150, 16), 256 threads.
// ---------------------------------------------------------------------------
__global__ __launch_bounds__(256) void vfrag_kernel(
    const float* __restrict__ vcA, const float* __restrict__ csA,
    unsigned short* __restrict__ vfA,
    const float* __restrict__ vcB, const float* __restrict__ csB,
    unsigned short* __restrict__ vfB)
{
    const int sel = blockIdx.y >> 3;
    const float* vc = sel ? vcB : vcA;
    const float* cs = sel ? csB : csA;
    unsigned short* vf = sel ? vfB : vfA;
    __shared__ float vl[32][33];
    __shared__ float ul[32];
    const int mt = blockIdx.x;
    const int h = blockIdx.y & 7;
    const int t = threadIdx.x;
    const int m0 = mt * 32;
    const float* vcbase = vc + (size_t)(h * N_TOK + m0) * HD;
    for (int e = t; e < 32 * HD; e += 256) vl[e >> 5][e & 31] = vcbase[e];
    if (t < 32) ul[t] = 1.0f / cs[(size_t)h * N_TOK + m0 + t];
    __syncthreads();
    const int b = t >> 6, lane = t & 63;
    const int hi5 = lane >> 5, lr = lane & 31;
    const int d = (b >> 1) * 32 + lr;       // 0..63 (>=38 zero pad)
    const int mb = (b & 1) * 16 + hi5 * 8;  // k-offset within tile
    union { unsigned short s[8]; s8v v; } pk;
#pragma unroll
    for (int j = 0; j < 8; ++j) {
        const int mo = mb + j;
        float v;
        if (d < 32)      v = vl[mo][d];
        else if (d < 38) v = posv(m0 + mo, d - 32);
        else             v = 0.0f;
        pk.s[j] = f2bf(v * ul[mo]);
    }
    *(s8v*)(vf + ((size_t)(h * NTILES + mt) * 4 + b) * 512 + lane * 8) = pk.v;
}

// ---------------------------------------------------------------------------
// Pass 2 (both fundamentals): S'^T = K.Q'^T; e = 2^S'; rs += e (packed f32);
// P' = e*e packed in-register (cvt_pk + permlane32_swap); T' += P'.vfrag via
// MFMA. 2-slot software pipeline: compute slot c, refill slot c with tile
// it+2 (~2-iter latency cover). 3-wave blocks share K/V streams via L1;
// 3 m-chunks with separate bf16 T partials (lane-pair packed plain stores).
// grid (50, 3, 16) XCD-swizzled, 192 thr. Overruns <= 2 tiles -- pad rule.
// ---------------------------------------------------------------------------
__global__ __launch_bounds__(192, 4) void tprime_mfma_kernel(
    const unsigned short* __restrict__ qbA, const unsigned short* __restrict__ kbA,
    const unsigned short* __restrict__ vfA, float* __restrict__ rsA,
    unsigned short* __restrict__ TA0, unsigned short* __restrict__ TA1,
    unsigned short* __restrict__ TA2,
    const unsigned short* __restrict__ qbB, const unsigned short* __restrict__ kbB,
    const unsigned short* __restrict__ vfB, float* __restrict__ rsB,
    unsigned short* __restrict__ TB0, unsigned short* __restrict__ TB1,
    unsigned short* __restrict__ TB2)
{
    int bx, by, bz;
    swzdec<50, MCHUNK, 16>(bx, by, bz);
    const int sel = bz >> 3;
    const unsigned short* qb = sel ? qbB : qbA;
    const unsigned short* kb = sel ? kbB : kbA;
    const unsigned short* vf = sel ? vfB : vfA;
    float* rs = sel ? rsB : rsA;
    unsigned short* T = sel ? (by == 0 ? TB0 : (by == 1 ? TB1 : TB2))
                            : (by == 0 ? TA0 : (by == 1 ? TA1 : TA2));
    const int lane = threadIdx.x & 63;
    const int wid = threadIdx.x >> 6;
    const int h = bz & 7;
    const int n0 = bx * 96 + wid * 32;
    const int lr = lane & 31, hi5 = lane >> 5;
    const int hbase = h * N_TOK;
    // Q as B operand (hoisted across the m-loop)
    const unsigned short* qp = qb + (hbase + n0 + lr) * HD + 8 * hi5;
    const s8v bQ0 = *(const s8v*)(qp);
    const s8v bQ1 = *(const s8v*)(qp + 16);
    f32x16 t0 = {}, t1 = {};
    const int mt0 = by * 50;
    const unsigned short* kp = kb + (hbase + mt0 * 32 + lr) * HD + 8 * hi5;
    const unsigned short* vp = vf + (size_t)(h * NTILES + mt0) * FRAG + lane * 8;
    s8v a0[2], a1[2], v00[2], v01[2], v10[2], v11[2];
#pragma unroll
    for (int j = 0; j < 2; ++j) {
        a0[j] = *(const s8v*)(kp);
        a1[j] = *(const s8v*)(kp + 16);
        v00[j] = *(const s8v*)(vp);
        v01[j] = *(const s8v*)(vp + 512);
        v10[j] = *(const s8v*)(vp + 1024);
        v11[j] = *(const s8v*)(vp + 1536);
        kp += 32 * HD;
        vp += FRAG;
    }
    f32x2 rsa = {0.f, 0.f}, rsb = {0.f, 0.f};
#pragma unroll 2
    for (int it = 0; it < 50; ++it) {
        const int c = it & 1;
        f32x16 s = {};
        s = MFMA(a0[c], bQ0, s);
        s = MFMA(a1[c], bQ1, s);
        f32x2 p2[8];
#pragma unroll
        for (int k = 0; k < 8; ++k) {
            f32x2 e2;
            e2.x = EXP2F(s[2 * k]);
            e2.y = EXP2F(s[2 * k + 1]);
            if (k & 1) rsb += e2; else rsa += e2;
            p2[k] = e2 * e2;
        }
        const int L0 = cvtpk(p2[0].x, p2[0].y), L1 = cvtpk(p2[1].x, p2[1].y);
        const int H0 = cvtpk(p2[2].x, p2[2].y), H1 = cvtpk(p2[3].x, p2[3].y);
        const int L2 = cvtpk(p2[4].x, p2[4].y), L3 = cvtpk(p2[5].x, p2[5].y);
        const int H2 = cvtpk(p2[6].x, p2[6].y), H3 = cvtpk(p2[7].x, p2[7].y);
        const i2v s0 = __builtin_amdgcn_permlane32_swap(L0, H0, false, false);
        const i2v s1 = __builtin_amdgcn_permlane32_swap(L1, H1, false, false);
        const i2v s2 = __builtin_amdgcn_permlane32_swap(L2, H2, false, false);
        const i2v s3 = __builtin_amdgcn_permlane32_swap(L3, H3, false, false);
        const s8v pa0 = mk_s8(s0[0], s1[0], s0[1], s1[1]);   // k = 0..15
        const s8v pa1 = mk_s8(s2[0], s3[0], s2[1], s3[1]);   // k = 16..31
        __builtin_amdgcn_s_setprio(1);
        t0 = MFMA(pa0, v00[c], t0);
        t0 = MFMA(pa1, v01[c], t0);
        t1 = MFMA(pa0, v10[c], t1);
        t1 = MFMA(pa1, v11[c], t1);
        __builtin_amdgcn_s_setprio(0);
        // refill slot c with tile it+2 (unconditional; pad rule covers end)
        a0[c] = *(const s8v*)(kp);
        a1[c] = *(const s8v*)(kp + 16);
        v00[c] = *(const s8v*)(vp);
        v01[c] = *(const s8v*)(vp + 512);
        v10[c] = *(const s8v*)(vp + 1024);
        v11[c] = *(const s8v*)(vp + 1536);
        kp += 32 * HD;
        vp += FRAG;
    }
    float rsacc = rsa.x + rsa.y + rsb.x + rsb.y;
    rsacc += __shfl_xor(rsacc, 32);
    if (lane < 32) atomicAdd(&rs[hbase + n0 + lane], rsacc);
    // T stored bf16: pair d=(2j,2j+1) packed via lane-xor-1 exchange,
    // even lanes store one dword (row layout [n][DP] bf16, DP/2 dwords/row)
    unsigned int* Tw = (unsigned int*)T;
#pragma unroll
    for (int r = 0; r < 16; ++r) {
        const int n = n0 + (r & 3) + 8 * (r >> 2) + 4 * hi5;
        const float par0 = __shfl_xor(t0[r], 1);
        const float par1 = __shfl_xor(t1[r], 1);
        if (!(lr & 1)) {
            Tw[(size_t)(hbase + n) * (DP / 2) + (lr >> 1)] =
                (unsigned int)cvtpk(t0[r], par0);
            if (lr < 8)
                Tw[(size_t)(hbase + n) * (DP / 2) + 16 + (lr >> 1)] =
                    (unsigned int)cvtpk(t1[r], par1);
        }
    }
}

// ---------------------------------------------------------------------------
// f[h,c,d] = sum_n (vc[n,c]/rs[n]) * (T0'+T1'+T2')[n,d] per 64-row chunk.
// T partials are bf16. vc cols 32..37 = inline pos. grid (16, 75).
// ---------------------------------------------------------------------------
__global__ __launch_bounds__(256) void fgemm_kernel(
    const float* __restrict__ VCA, const float* __restrict__ rsA,
    const unsigned short* __restrict__ TA0, const unsigned short* __restrict__ TA1,
    const unsigned short* __restrict__ TA2, float* __restrict__ fA,
    const float* __restrict__ VCB, const float* __restrict__ rsB,
    const unsigned short* __restrict__ TB0, const unsigned short* __restrict__ TB1,
    const unsigned short* __restrict__ TB2, float* __restrict__ fB)
{
    const int sel = blockIdx.x >> 3;
    const float* VC = sel ? VCB : VCA;
    const float* rs = sel ? rsB : rsA;
    const unsigned short* Ta = sel ? TB0 : TA0;
    const unsigned short* Tb = sel ? TB1 : TA1;
    const unsigned short* Tc = sel ? TB2 : TA2;
    float* f = sel ? fB : fA;
    __shared__ __align__(16) float wvcl[64 * DP];
    __shared__ __align__(16) float tl[64 * DP];
    __shared__ float wl[64];
    const int h = blockIdx.x & 7, n0 = blockIdx.y * 64;
    const int t = threadIdx.x;
    if (t < 64) wl[t] = 1.0f / rs[(size_t)h * N_TOK + n0 + t];
    __syncthreads();
    const float* vcbase = VC + (size_t)(h * N_TOK + n0) * HD;
    const ushort4* ta4 = (const ushort4*)(Ta + (size_t)(h * N_TOK + n0) * DP);
    const ushort4* tb4 = (const ushort4*)(Tb + (size_t)(h * N_TOK + n0) * DP);
    const ushort4* tc4 = (const ushort4*)(Tc + (size_t)(h * N_TOK + n0) * DP);
    for (int e4 = t; e4 < 64 * DP / 4; e4 += 256) {
        const ushort4 a4 = ta4[e4];
        const ushort4 b4 = tb4[e4];
        const ushort4 c4 = tc4[e4];
        tl[e4 * 4 + 0] = bf2f(a4.x) + bf2f(b4.x) + bf2f(c4.x);
        tl[e4 * 4 + 1] = bf2f(a4.y) + bf2f(b4.y) + bf2f(c4.y);
        tl[e4 * 4 + 2] = bf2f(a4.z) + bf2f(b4.z) + bf2f(c4.z);
        tl[e4 * 4 + 3] = bf2f(a4.w) + bf2f(b4.w) + bf2f(c4.w);
    }
    for (int e = t; e < 64 * DP; e += 256) {
        const int row = e / DP, c = e - row * DP;
        float v;
        if (c < 32)      v = vcbase[row * HD + c];
        else if (c < 38) v = posv(n0 + row, c - 32);
        else             v = 0.0f;
        wvcl[e] = v * wl[row];
    }
    __syncthreads();
    for (int p = t; p < DD * DD; p += 256) {
        const int c = p / DD, d = p % DD;
        float s = 0.f;
#pragma unroll 8
        for (int n = 0; n < 64; ++n) s += wvcl[n * DP + c] * tl[n * DP + d];
        atomicAdd(&f[(size_t)(h * DD + c) * DP + d], s);
    }
}

// ---------------------------------------------------------------------------
// out[d,e] = sum_j f[j,d] * proj_w[e,j] + proj_b[e]. Both fundamentals:
// grid (38, 2); y=0 -> f1 -> out+DD*256, y=1 -> f2 -> out.
// ---------------------------------------------------------------------------
__global__ __launch_bounds__(256) void out_kernel(
    const float* __restrict__ f1, const float* __restrict__ f2,
    const float* __restrict__ pw, const float* __restrict__ pb,
    float* __restrict__ out)
{
    const int sel = blockIdx.y;
    const float* f = sel ? f2 : f1;
    float* dst = sel ? out : (out + DD * 256);
    __shared__ __align__(16) float flds[304];
    const int d = blockIdx.x, t = threadIdx.x;
    for (int j = t; j < 304; j += 256) flds[j] = f[(size_t)j * DP + d];
    __syncthreads();
    float acc = pb[t];
    const float* pwrow = pw + (size_t)t * 304;
#pragma unroll 4
    for (int j = 0; j < 304; j += 4) {
        const float4 p4 = *(const float4*)&pwrow[j];
        const float4 f4 = *(const float4*)&flds[j];
        acc += p4.x * f4.x + p4.y * f4.y + p4.z * f4.z + p4.w * f4.w;
    }
    dst[(size_t)d * 256 + t] = acc;
}

extern "C" void kernel_launch(void* const* d_in, const int* in_sizes, int n_in,
                              void* d_out, int out_size, void* d_ws, size_t ws_size,
                              hipStream_t stream)
{
    const float* x1 = (const float*)d_in[0];
    const float* x2 = (const float*)d_in[1];
    const float* qkv_w = (const float*)d_in[2];
    const float* proj_w = (const float*)d_in[3];
    const float* proj_b = (const float*)d_in[4];
    float* out = (float*)d_out;

    const size_t QSZ = (size_t)NH * N_TOK * HD;          // 1,228,800
    const size_t VSZ = (size_t)NH * N_TOK * DP;          // 1,536,000
    const size_t SSZ = (size_t)NH * N_TOK;               //    38,400
    const size_t FSZ = (size_t)NH * DD * DP;             //    12,160
    const size_t XSZ = (size_t)N_TOK * 256;              // 1,228,800
    const size_t WSZ = (size_t)768 * 256;                //   196,608
    const size_t VTSZ = (size_t)NH * NTILES * FRAG;      // 2,457,600

    // fp32 region
    float* vc1 = (float*)d_ws;          // [h][4800][32]
    float* vc2 = vc1 + QSZ;
    float* rs1 = vc2 + QSZ;   // zeroed region starts here
    float* cs1 = rs1 + SSZ;
    float* rs2 = cs1 + SSZ;
    float* cs2 = rs2 + SSZ;
    float* f1 = cs2 + SSZ;
    float* f2 = f1 + FSZ;     // zeroed region ends at f2 + FSZ
    // bf16 region -- ORDER MATTERS: unconditional prefetches overrun each
    // buffer by <= 2 tiles into the next allocated buffer.
    unsigned short* xh1 = (unsigned short*)(f2 + FSZ);
    unsigned short* xh2 = xh1 + XSZ;
    unsigned short* wh = xh2 + XSZ;
    unsigned short* qb1 = wh + WSZ;
    unsigned short* kb1 = qb1 + QSZ;    // qb1 overrun -> kb1
    unsigned short* qb2 = kb1 + QSZ;    // kb1 overrun -> qb2
    unsigned short* kb2 = qb2 + QSZ;    // qb2 overrun -> kb2
    unsigned short* vf1 = kb2 + QSZ;    // kb2 overrun -> vf1
    unsigned short* vf2 = vf1 + VTSZ;   // vf1 overrun -> vf2
    unsigned short* T1a = vf2 + VTSZ;   // vf2 overrun -> T1a (values unused)
    unsigned short* T1b = T1a + VSZ;    // T partials (bf16), fully overwritten
    unsigned short* T1c = T1b + VSZ;
    unsigned short* T2a = T1c + VSZ;
    unsigned short* T2b = T2a + VSZ;
    unsigned short* T2c = T2b + VSZ;

    const int zn4 = (int)((4 * SSZ + 2 * FSZ) / 4);   // float4 count to zero

    frag_kernel<<<324 + 174, 256, 0, stream>>>(x1, xh1, x2, xh2, qkv_w, wh,
                                               rs1, zn4);

    qkv_mfma_kernel<<<dim3(75, 12, 2), 128, 0, stream>>>(
        xh1, qb1, kb1, vc1, xh2, qb2, kb2, vc2, wh);

    // fundamental_1 = f(q2, k1, vc1); fundamental_2 = f(q1, k2, vc2)
    cs_kernel<<<dim3(25, 5, 16), 192, 0, stream>>>(qb2, kb1, cs1,
                                                   qb1, kb2, cs2);
    vfrag_kernel<<<dim3(150, 16), 256, 0, stream>>>(vc1, cs1, vf1,
                                                    vc2, cs2, vf2);
    tprime_mfma_kernel<<<dim3(50, MCHUNK, 16), 192, 0, stream>>>(
        qb2, kb1, vf1, rs1, T1a, T1b, T1c,
        qb1, kb2, vf2, rs2, T2a, T2b, T2c);
    fgemm_kernel<<<dim3(16, 75), 256, 0, stream>>>(
        vc1, rs1, T1a, T1b, T1c, f1,
        vc2, rs2, T2a, T2b, T2c, f2);
    out_kernel<<<dim3(38, 2), 256, 0, stream>>>(f1, f2, proj_w, proj_b, out);
}